// Round 15
// baseline (1557.302 us; speedup 1.0000x reference)
//
#include <hip/hip_runtime.h>
#include <hip/hip_bf16.h>
#include <cstdint>

#define DEV static __device__ __forceinline__

typedef __attribute__((ext_vector_type(8))) short bf16x8;
typedef __attribute__((ext_vector_type(4))) float f32x4;

// ---------- bf16 helpers (bit-level) ----------
DEV unsigned short f2bf(float f) {
  union { float f; unsigned u; } c; c.f = f;
  unsigned u = c.u;
  return (unsigned short)((u + 0x7fffu + ((u >> 16) & 1u)) >> 16);  // RNE
}
DEV float bf2f(unsigned short h) {
  union { unsigned u; float f; } c; c.u = ((unsigned)h) << 16; return c.f;
}
DEV float bflo(unsigned u) { union { unsigned u; float f; } c; c.u = u << 16; return c.f; }
DEV float bfhi(unsigned u) { union { unsigned u; float f; } c; c.u = u & 0xffff0000u; return c.f; }
// fast round-half-up bf16 pair pack: lo16 = bf(a), hi16 = bf(b), 3 VALU ops
DEV unsigned pack_bf16(float a, float b) {
  union { float f; unsigned u; } ca, cb; ca.f = a; cb.f = b;
  return __builtin_amdgcn_perm(cb.u + 0x8000u, ca.u + 0x8000u, 0x07060302u);
}

// async global->LDS, 16B per lane; LDS dest is wave-uniform base + lane*16
#define ASYNC_COPY16(gsrc, ldst)                                                      \
  __builtin_amdgcn_global_load_lds(                                                   \
      (const __attribute__((address_space(1))) void*)(unsigned long long)(gsrc),      \
      (__attribute__((address_space(3))) void*)(unsigned int)(unsigned long long)(ldst), \
      16, 0, 0)

// =====================================================================
// fp32 -> bf16 weight conversion, all four weight tensors in ONE launch
// (ranges: qkv 4608 blocks, out 1536, ff1 6144, ff2 6144 -> 18432)
// =====================================================================
__global__ void cvt_all_kernel(const float* __restrict__ s0, unsigned short* __restrict__ d0,
                               const float* __restrict__ s1, unsigned short* __restrict__ d1,
                               const float* __restrict__ s2, unsigned short* __restrict__ d2,
                               const float* __restrict__ s3, unsigned short* __restrict__ d3) {
  const int blk = blockIdx.x;
  const float* s; unsigned short* d; int base;
  if (blk < 4608)       { s = s0; d = d0; base = blk; }
  else if (blk < 6144)  { s = s1; d = d1; base = blk - 4608; }
  else if (blk < 12288) { s = s2; d = d2; base = blk - 6144; }
  else                  { s = s3; d = d3; base = blk - 12288; }
  size_t i = ((size_t)base * 256 + threadIdx.x) * 4;
  float4 v = *(const float4*)(s + i);
  d[i + 0] = f2bf(v.x);
  d[i + 1] = f2bf(v.y);
  d[i + 2] = f2bf(v.z);
  d[i + 3] = f2bf(v.w);
}

// =====================================================================
// embedding + positional encoding -> xb bf16 (residual stream is bf16)
// =====================================================================
__global__ void embed_kernel(const float* __restrict__ src,    // [B*S,16]
                             const float* __restrict__ emb_w,  // [512,16]
                             const float* __restrict__ emb_b,  // [512]
                             unsigned short* __restrict__ xb) {
  const int bs = blockIdx.x;        // 0..16383
  const int d = threadIdx.x;        // 0..511
  const int s = bs & 255;
  __shared__ float sv[16];
  if (d < 16) sv[d] = src[(size_t)bs * 16 + d];
  __syncthreads();
  const float* wr = emb_w + (size_t)d * 16;
  float acc = emb_b[d];
#pragma unroll
  for (int v = 0; v < 16; v++) acc += sv[v] * wr[v];
  const float den = __expf(-(float)(d & ~1) * (9.2103403719761836f / 512.f));
  const float arg = (float)s * den;
  acc += (d & 1) ? __cosf(arg) : __sinf(arg);
  xb[(size_t)bs * 512 + d] = f2bf(acc);
}

// =====================================================================
// Phased + counted-vmcnt bf16 MFMA GEMM, NT: C = A.B^T + bias (+relu).
// BM=128, BN=256, BK=64, 512 thr = 8 waves (2M x 4N), wave tile 64x64.
// THREE LDS buffers rotate (depth-2: tile kt+2 staged during tile kt);
// vmcnt(6) ONLY at tile entry (never 0 mid-loop).  Each K-tile runs 4
// phases (kh x nh): {ds_read subtile || 1-2 stage issues -> barrier ->
// lgkmcnt(0) -> setprio(1) 8xMFMA setprio(0) -> barrier}.  This is the
// m218-verified combo: phase role-split + counted drain (r4 had phases
// with drain-0 = null; r8 had counted drain without phases = null).
// Race safety: stage targets buf(kt+2)%3 == buf(kt-1)%3 whose ds_reads
// drained at each phase's lgkmcnt(0) before tile kt's entry barrier.
// XOR chunk swizzle (row stride 128B): slot s of row r holds global
// chunk s^(r&7); readers use (kh*4+quad)^(r16&7).
// Operands swapped (A_op = weights) so lane's 4 acc regs = 4 consec n.
// =====================================================================
template <int BM, int RELU>
__global__ __launch_bounds__(512, 2) void gemm_pipe(
    const unsigned short* __restrict__ A,   // [M,K] bf16 activations
    const unsigned short* __restrict__ B,   // [N,K] bf16 weights
    const float* __restrict__ bias,         // [N]
    unsigned short* __restrict__ Cb,        // [M,N] bf16 out
    int M, int N, int K) {
  constexpr int BN = 256;
  constexpr int MT = BM / 32;        // 4 m-frags per wave
  constexpr int NT = 4;              // 4 n-frags per wave
  constexpr int NLA = BM / 64;       // 2 A-chunk loads per K-tile
  constexpr int NL = NLA + BN / 64;  // + 4 B-chunks = 6 loads per K-tile
  constexpr int BUFE = (BM + BN) * 64;  // 24576 elems = 48KB per buffer
  __shared__ unsigned short lds[3 * BUFE];  // 144KB, 1 block/CU

  const int tid = threadIdx.x;
  const int lane = tid & 63;
  const int w = tid >> 6;      // 0..7
  const int wmi = w >> 2;      // 0..1
  const int wni = w & 3;       // 0..3
  const int r16 = lane & 15;
  const int quad = lane >> 4;
  const int rsw = r16 & 7;
  const int m0 = blockIdx.x * BM;   // m fast -> XCD locality for A
  const int n0 = blockIdx.y * BN;

  const int srow = tid >> 3;
  const int scol = ((tid & 7) ^ (srow & 7)) * 8;
  const unsigned short* gA = A + (size_t)(m0 + srow) * K + scol;
  const unsigned short* gB = B + (size_t)(n0 + srow) * K + scol;

#define STG(i, bufi, kc)                                                        \
  do {                                                                          \
    if ((i) < NLA)                                                              \
      ASYNC_COPY16(gA + (size_t)((i) * 64) * K + (kc),                          \
                   lds + (bufi) * BUFE + ((i) * 64 + w * 8) * 64);              \
    else                                                                        \
      ASYNC_COPY16(gB + (size_t)(((i) - NLA) * 64) * K + (kc),                  \
                   lds + (bufi) * BUFE + (BM + ((i) - NLA) * 64 + w * 8) * 64); \
  } while (0)

  f32x4 acc[MT][NT] = {};  // acc[i][j]: D[n=quad*4+r][m=r16]

  const int NK = K >> 6;
  // prologue: stage tiles 0 and 1 (12 loads in flight)
#pragma unroll
  for (int i = 0; i < NL; ++i) STG(i, 0, 0);
#pragma unroll
  for (int i = 0; i < NL; ++i) STG(i, 1, 64);

  for (int kt = 0; kt < NK; ++kt) {
    const int buf = kt % 3;
    // counted drain: tile kt's 6 loads landed; kt+1's stay in flight
    if (kt + 1 < NK)
      asm volatile("s_waitcnt vmcnt(%0)" ::"i"(NL) : "memory");
    else
      asm volatile("s_waitcnt vmcnt(0)" ::: "memory");
    __builtin_amdgcn_s_barrier();
    const int doSt = (kt + 2 < NK);
    const int sb = (kt + 2) % 3;
    const int kc = (kt + 2) << 6;
    const unsigned short* As = lds + buf * BUFE;
    const unsigned short* Bs = As + BM * 64;
#pragma unroll
    for (int kh = 0; kh < 2; ++kh) {
      bf16x8 aR[MT];
#pragma unroll
      for (int nh = 0; nh < 2; ++nh) {
        const int ph = kh * 2 + nh;
        const int ko = ((kh * 4 + quad) ^ rsw) * 8;
        if (nh == 0) {
#pragma unroll
          for (int m = 0; m < MT; ++m)
            aR[m] = *(const bf16x8*)(As + (wmi * 64 + m * 16 + r16) * 64 + ko);
        }
        bf16x8 bR[2];
#pragma unroll
        for (int j = 0; j < 2; ++j)
          bR[j] = *(const bf16x8*)(Bs + (wni * 64 + (nh * 2 + j) * 16 + r16) * 64 + ko);
        if (doSt) {
          if (ph == 0) { STG(0, sb, kc); STG(1, sb, kc); }
          else if (ph == 1) { STG(2, sb, kc); STG(3, sb, kc); }
          else if (ph == 2) { STG(4, sb, kc); }
          else { STG(5, sb, kc); }
        }
        __builtin_amdgcn_s_barrier();
        asm volatile("s_waitcnt lgkmcnt(0)" ::: "memory");
        __builtin_amdgcn_s_setprio(1);
#pragma unroll
        for (int m = 0; m < MT; ++m)
#pragma unroll
          for (int j = 0; j < 2; ++j)
            acc[m][nh * 2 + j] = __builtin_amdgcn_mfma_f32_16x16x32_bf16(
                bR[j], aR[m], acc[m][nh * 2 + j], 0, 0, 0);
        __builtin_amdgcn_s_setprio(0);
        __builtin_amdgcn_s_barrier();
      }
    }
  }
#undef STG

  const int mb = m0 + wmi * 64 + r16;
  const int nb = n0 + wni * 64 + quad * 4;
#pragma unroll
  for (int j = 0; j < NT; ++j) {
    const int n = nb + j * 16;
    const float4 bv = *(const float4*)(bias + n);
#pragma unroll
    for (int i = 0; i < MT; ++i) {
      const size_t off = (size_t)(mb + i * 16) * N + n;
      float4 v;
      v.x = acc[i][j][0] + bv.x;
      v.y = acc[i][j][1] + bv.y;
      v.z = acc[i][j][2] + bv.z;
      v.w = acc[i][j][3] + bv.w;
      if (RELU) {
        v.x = fmaxf(v.x, 0.f); v.y = fmaxf(v.y, 0.f);
        v.z = fmaxf(v.z, 0.f); v.w = fmaxf(v.w, 0.f);
      }
      uint2 u;
      u.x = pack_bf16(v.x, v.y);
      u.y = pack_bf16(v.z, v.w);
      *(uint2*)(Cb + off) = u;
    }
  }
}

// =====================================================================
// GEMM + residual + LayerNorm fused (for the two N=512 projections):
// xb[m][:] = LN(A.B^T + bias + xb)[m][:] * g + beta, bf16 out in place.
// BM=64, BN=512, BK=64, 512 thr = 8 waves (wave w owns cols w*64..+63,
// all 64 rows).  A block owns FULL rows -> LN in epilogue.
// [round-13 measured win — unchanged]
// =====================================================================
__global__ __launch_bounds__(512, 2) void gemm_ln(
    const unsigned short* __restrict__ A,    // [M,K] bf16
    const unsigned short* __restrict__ B,    // [512,K] bf16 weights
    const float* __restrict__ bias,          // [512]
    const float* __restrict__ g,             // [512] ln gamma
    const float* __restrict__ beta,          // [512] ln beta
    unsigned short* __restrict__ xb,         // [M,512] residual in / out
    int K) {
  constexpr int BM = 64;
  constexpr int MT = 4;                 // 4 m-frags (rows i*16+r16)
  constexpr int NT = 4;                 // 4 n-frags per wave (64 cols)
  constexpr int NL = 1 + 8;             // 1 A-chunk + 8 B-chunks per K-tile
  constexpr int BUFE = (BM + 512) * 64; // 36864 elems = 72KB per buffer
  __shared__ unsigned short lds[2 * BUFE];  // 147456 B

  const int tid = threadIdx.x;
  const int lane = tid & 63;
  const int w = tid >> 6;     // 0..7: wave's col block = w*64
  const int r16 = lane & 15;
  const int quad = lane >> 4;
  const int rsw = r16 & 7;
  const int m0 = blockIdx.x * BM;

  const int srow = tid >> 3;
  const int scol = ((tid & 7) ^ (srow & 7)) * 8;
  const unsigned short* gA = A + (size_t)(m0 + srow) * K + scol;
  const unsigned short* gB = B + (size_t)srow * K + scol;

#define STG2(i, bufi, kc)                                                       \
  do {                                                                          \
    if ((i) == 0)                                                               \
      ASYNC_COPY16(gA + (size_t)(kc), lds + (bufi) * BUFE + (w * 8) * 64);      \
    else                                                                        \
      ASYNC_COPY16(gB + (size_t)(((i) - 1) * 64) * K + (kc),                    \
                   lds + (bufi) * BUFE + (BM + ((i) - 1) * 64 + w * 8) * 64);   \
  } while (0)

  f32x4 acc[MT][NT] = {};  // acc[i][j]: D[n=quad*4+r][m=r16]

  const int NK = K >> 6;
  // prologue: stage tile 0 -> buf 0
#pragma unroll
  for (int i = 0; i < NL; ++i) STG2(i, 0, 0);

  for (int kt = 0; kt < NK; ++kt) {
    const int buf = kt & 1;
    // stage kt+1 into buf^1 (freed by previous iter's trailing barrier)
    if (kt + 1 < NK) {
      const int kc = (kt + 1) << 6;
#pragma unroll
      for (int i = 0; i < NL; ++i) STG2(i, buf ^ 1, kc);
      asm volatile("s_waitcnt vmcnt(%0)" ::"i"(NL) : "memory");  // tile kt landed
    } else {
      asm volatile("s_waitcnt vmcnt(0)" ::: "memory");
    }
    __builtin_amdgcn_s_barrier();  // all waves' tile-kt loads landed
    const unsigned short* As = lds + buf * BUFE;
    const unsigned short* Bs = As + BM * 64;
#pragma unroll
    for (int kh = 0; kh < 2; ++kh) {
      const int ko = ((kh * 4 + quad) ^ rsw) * 8;
      bf16x8 aR[MT], bR[NT];
#pragma unroll
      for (int m = 0; m < MT; ++m)
        aR[m] = *(const bf16x8*)(As + (m * 16 + r16) * 64 + ko);
#pragma unroll
      for (int j = 0; j < NT; ++j)
        bR[j] = *(const bf16x8*)(Bs + (w * 64 + j * 16 + r16) * 64 + ko);
      __builtin_amdgcn_s_setprio(1);
#pragma unroll
      for (int m = 0; m < MT; ++m)
#pragma unroll
        for (int j = 0; j < NT; ++j)
          acc[m][j] = __builtin_amdgcn_mfma_f32_16x16x32_bf16(
              bR[j], aR[m], acc[m][j], 0, 0, 0);
      __builtin_amdgcn_s_setprio(0);
    }
    // all our ds_reads of buf done; barrier frees buf for the next restage
    asm volatile("s_waitcnt lgkmcnt(0)" ::: "memory");
    __builtin_amdgcn_s_barrier();
  }
#undef STG2

  // ---- epilogue: z = acc + bias + res; row LN; write xb bf16 ----
  // lane holds rows m = i*16+r16 (i=0..3), cols n = w*64 + j*16 + quad*4 + r
  const int nb = w * 64 + quad * 4;
  float psum[MT] = {}, psq[MT] = {};
#pragma unroll
  for (int j = 0; j < NT; ++j) {
    const int n = nb + j * 16;
    const float4 bv = *(const float4*)(bias + n);
#pragma unroll
    for (int i = 0; i < MT; ++i) {
      const size_t off = (size_t)(m0 + i * 16 + r16) * 512 + n;
      const uint2 ru = *(const uint2*)(xb + off);
      f32x4 v;
      v[0] = acc[i][j][0] + bv.x + bflo(ru.x);
      v[1] = acc[i][j][1] + bv.y + bfhi(ru.x);
      v[2] = acc[i][j][2] + bv.z + bflo(ru.y);
      v[3] = acc[i][j][3] + bv.w + bfhi(ru.y);
      acc[i][j] = v;  // keep z in regs
#pragma unroll
      for (int r = 0; r < 4; ++r) {
        psum[i] += v[r];
        psq[i] += v[r] * v[r];
      }
    }
  }
  // quad-reduce (lanes quad*16+r16 share a row set)
#pragma unroll
  for (int i = 0; i < MT; ++i) {
    psum[i] += __shfl_xor(psum[i], 16);
    psum[i] += __shfl_xor(psum[i], 32);
    psq[i] += __shfl_xor(psq[i], 16);
    psq[i] += __shfl_xor(psq[i], 32);
  }
  // cross-wave via LDS (staging buffers are dead: trailing barrier passed)
  float* redS = (float*)lds;          // [8][64]
  float* redQ = redS + 512;           // [8][64]
  if (quad == 0) {
#pragma unroll
    for (int i = 0; i < MT; ++i) {
      redS[w * 64 + i * 16 + r16] = psum[i];
      redQ[w * 64 + i * 16 + r16] = psq[i];
    }
  }
  __syncthreads();
  float mu[MT], rs[MT];
#pragma unroll
  for (int i = 0; i < MT; ++i) {
    const int row = i * 16 + r16;
    float s = 0.f, q = 0.f;
#pragma unroll
    for (int ww = 0; ww < 8; ++ww) {
      s += redS[ww * 64 + row];
      q += redQ[ww * 64 + row];
    }
    mu[i] = s * (1.f / 512.f);
    rs[i] = rsqrtf(q * (1.f / 512.f) - mu[i] * mu[i] + 1e-5f);
  }
#pragma unroll
  for (int j = 0; j < NT; ++j) {
    const int n = nb + j * 16;
    const float4 gv = *(const float4*)(g + n);
    const float4 be = *(const float4*)(beta + n);
#pragma unroll
    for (int i = 0; i < MT; ++i) {
      const size_t off = (size_t)(m0 + i * 16 + r16) * 512 + n;
      const f32x4 v = acc[i][j];
      float o0 = (v[0] - mu[i]) * rs[i] * gv.x + be.x;
      float o1 = (v[1] - mu[i]) * rs[i] * gv.y + be.y;
      float o2 = (v[2] - mu[i]) * rs[i] * gv.z + be.z;
      float o3 = (v[3] - mu[i]) * rs[i] * gv.w + be.w;
      uint2 u;
      u.x = pack_bf16(o0, o1);
      u.y = pack_bf16(o2, o3);
      *(uint2*)(xb + off) = u;
    }
  }
}

// =====================================================================
// Fused attention: one block per (b,h). V^T staged once (33.8KB);
// loop over 8 q-tiles of 32: S^T scores (wave = k-quarter, A=K, B=Q from
// global), two-phase LDS softmax (max then sum), P packed to LDS (16.9KB,
// stride 264 -> 2-way reads), PV as O^T = Vt.P, uint2 packed O stores.
// [round-8 version, verbatim]
// =====================================================================
__global__ __launch_bounds__(256, 2) void attn_fused(
    const unsigned short* __restrict__ qkv,  // [B*S,1536] bf16 q|k|v
    unsigned short* __restrict__ O) {        // [B*S,512] bf16
  __shared__ unsigned short Vt[64 * 264];  // V^T[d][k], stride 264
  __shared__ unsigned short Pl[32 * 264];  // P[q][k],  stride 264
  __shared__ float redM[4][32];
  __shared__ float redS[4][32];
  const int tid = threadIdx.x;
  const int lane = tid & 63;
  const int w = tid >> 6;
  const int r16 = lane & 15;
  const int quad = lane >> 4;
  const int h = blockIdx.x & 7;
  const int b = blockIdx.x >> 3;

  // stage V^T (verified round-2 pattern)
  {
    const int kp = w * 32 + (lane & 31);
    const int dhalf = lane >> 5;
    const unsigned short* vbase =
        qkv + (size_t)(b * 256 + 2 * kp) * 1536 + 1024 + h * 64;
    unsigned* dst = (unsigned*)Vt;
#pragma unroll
    for (int t = 0; t < 4; t++) {
      const int dc = dhalf + 2 * t;  // d-chunk 0..7
      const uint4 a = *(const uint4*)(vbase + dc * 8);
      const uint4 bb = *(const uint4*)(vbase + 1536 + dc * 8);
      const unsigned* ap = (const unsigned*)&a;
      const unsigned* bp = (const unsigned*)&bb;
#pragma unroll
      for (int i = 0; i < 4; i++) {
        const unsigned lo = ap[i], hi = bp[i];
        dst[(dc * 8 + 2 * i) * 132 + kp] = (lo & 0xffffu) | (hi << 16);
        dst[(dc * 8 + 2 * i + 1) * 132 + kp] = (lo >> 16) | (hi & 0xffff0000u);
      }
    }
  }
  __syncthreads();

  const unsigned short* krow =
      qkv + (size_t)(b * 256 + r16) * 1536 + 512 + h * 64 + quad * 8;
  const unsigned short* qrow =
      qkv + (size_t)(b * 256 + r16) * 1536 + h * 64 + quad * 8;

  for (int qt = 0; qt < 8; qt++) {
    const int q0 = qt * 32;
    f32x4 acc[4][2] = {};  // acc[mt][nt]: S^T[k=w*64+mt*16+quad*4+r][q=q0+nt*16+r16]
    bf16x8 bQ0[2], bQ1[2];
#pragma unroll
    for (int nt = 0; nt < 2; nt++) {
      const unsigned short* qp = qrow + (size_t)(q0 + nt * 16) * 1536;
      bQ0[nt] = *(const bf16x8*)(qp);
      bQ1[nt] = *(const bf16x8*)(qp + 32);
    }
#pragma unroll
    for (int mt = 0; mt < 4; mt++) {
      const unsigned short* kp = krow + (size_t)(w * 64 + mt * 16) * 1536;
      const bf16x8 aK0 = *(const bf16x8*)(kp);
      const bf16x8 aK1 = *(const bf16x8*)(kp + 32);
#pragma unroll
      for (int nt = 0; nt < 2; nt++) {
        acc[mt][nt] = __builtin_amdgcn_mfma_f32_16x16x32_bf16(aK0, bQ0[nt], acc[mt][nt], 0, 0, 0);
        acc[mt][nt] = __builtin_amdgcn_mfma_f32_16x16x32_bf16(aK1, bQ1[nt], acc[mt][nt], 0, 0, 0);
      }
    }
#pragma unroll
    for (int nt = 0; nt < 2; nt++) {
      float m = acc[0][nt][0];
#pragma unroll
      for (int mt = 0; mt < 4; mt++)
#pragma unroll
        for (int r = 0; r < 4; r++) m = fmaxf(m, acc[mt][nt][r]);
      m = fmaxf(m, __shfl_xor(m, 16));
      m = fmaxf(m, __shfl_xor(m, 32));
      if (quad == 0) redM[w][nt * 16 + r16] = m;
    }
    __syncthreads();
    float mg[2], sw[2];
#pragma unroll
    for (int nt = 0; nt < 2; nt++) {
      const int q = nt * 16 + r16;
      mg[nt] = fmaxf(fmaxf(redM[0][q], redM[1][q]), fmaxf(redM[2][q], redM[3][q]));
      sw[nt] = 0.f;
    }
#pragma unroll
    for (int mt = 0; mt < 4; mt++)
#pragma unroll
      for (int nt = 0; nt < 2; nt++)
#pragma unroll
        for (int r = 0; r < 4; r++) {
          acc[mt][nt][r] = __expf((acc[mt][nt][r] - mg[nt]) * 0.125f);
          sw[nt] += acc[mt][nt][r];
        }
#pragma unroll
    for (int nt = 0; nt < 2; nt++) {
      sw[nt] += __shfl_xor(sw[nt], 16);
      sw[nt] += __shfl_xor(sw[nt], 32);
      if (quad == 0) redS[w][nt * 16 + r16] = sw[nt];
    }
    __syncthreads();
    float inv[2];
#pragma unroll
    for (int nt = 0; nt < 2; nt++) {
      const int q = nt * 16 + r16;
      inv[nt] = 1.f / (redS[0][q] + redS[1][q] + redS[2][q] + redS[3][q]);
    }
#pragma unroll
    for (int nt = 0; nt < 2; nt++) {
      unsigned short* prow = Pl + (nt * 16 + r16) * 264 + w * 64 + quad * 4;
#pragma unroll
      for (int mt = 0; mt < 4; mt++) {
        uint2 u;
        u.x = pack_bf16(acc[mt][nt][0] * inv[nt], acc[mt][nt][1] * inv[nt]);
        u.y = pack_bf16(acc[mt][nt][2] * inv[nt], acc[mt][nt][3] * inv[nt]);
        *(uint2*)(prow + mt * 16) = u;
      }
    }
    __syncthreads();
    f32x4 o[2] = {};
#pragma unroll
    for (int s = 0; s < 8; s++) {
      const bf16x8 aV = *(const bf16x8*)(Vt + (w * 16 + r16) * 264 + s * 32 + quad * 8);
#pragma unroll
      for (int nt = 0; nt < 2; nt++) {
        const bf16x8 bP = *(const bf16x8*)(Pl + (nt * 16 + r16) * 264 + s * 32 + quad * 8);
        o[nt] = __builtin_amdgcn_mfma_f32_16x16x32_bf16(aV, bP, o[nt], 0, 0, 0);
      }
    }
#pragma unroll
    for (int nt = 0; nt < 2; nt++) {
      uint2 u;
      u.x = pack_bf16(o[nt][0], o[nt][1]);
      u.y = pack_bf16(o[nt][2], o[nt][3]);
      *(uint2*)(O + (size_t)(b * 256 + q0 + nt * 16 + r16) * 512 + h * 64 +
                w * 16 + quad * 4) = u;
    }
  }
}

// =====================================================================
// latent: mem[64,256] += xb[64,131072](bf16) . W[256,131072]^T
// bf16 MFMA streaming, W converted fp32->bf16 in-flight, split-K atomics.
// =====================================================================
__global__ void zero_kernel(float* __restrict__ p) {
  p[blockIdx.x * 256 + threadIdx.x] = 0.f;
}

__global__ __launch_bounds__(256) void latent_gemm(
    const unsigned short* __restrict__ xb, const float* __restrict__ W,
    float* __restrict__ mem) {
  const int tid = threadIdx.x;
  const int lane = tid & 63;
  const int w = tid >> 6;
  const int r16 = lane & 15;
  const int quad = lane >> 4;
  const int n0 = blockIdx.x * 64 + w * 16;     // wave's 16 n-rows
  const int kc0 = blockIdx.y * 1024;

  const float* wrow = W + (size_t)(n0 + r16) * 131072 + kc0 + quad * 8;
  const unsigned short* xrow = xb + (size_t)r16 * 131072 + kc0 + quad * 8;

  f32x4 c[4] = {};  // C[b = i*16+quad*4+reg][n = n0+r16]
  for (int k = 0; k < 1024; k += 32) {
    const float4 wa = *(const float4*)(wrow + k);
    const float4 wb = *(const float4*)(wrow + k + 4);
    union { unsigned u[4]; bf16x8 v; } cw;
    cw.u[0] = pack_bf16(wa.x, wa.y);
    cw.u[1] = pack_bf16(wa.z, wa.w);
    cw.u[2] = pack_bf16(wb.x, wb.y);
    cw.u[3] = pack_bf16(wb.z, wb.w);
#pragma unroll
    for (int i = 0; i < 4; i++) {
      const bf16x8 aX = *(const bf16x8*)(xrow + (size_t)i * 2097152 + k);
      c[i] = __builtin_amdgcn_mfma_f32_16x16x32_bf16(aX, cw.v, c[i], 0, 0, 0);
    }
  }
#pragma unroll
  for (int i = 0; i < 4; i++)
#pragma unroll
    for (int r = 0; r < 4; r++)
      atomicAdd(&mem[(size_t)(i * 16 + quad * 4 + r) * 256 + n0 + r16], c[i][r]);
}

// =====================================================================
__global__ __launch_bounds__(256) void head_kernel(
    const float* __restrict__ mem, const float* __restrict__ lat_b,
    const float* __restrict__ head_w, const float* __restrict__ head_b,
    float* __restrict__ out) {
  const int b = blockIdx.x;
  const int tid = threadIdx.x;
  float v = (mem[(size_t)b * 256 + tid] + lat_b[tid]) * head_w[tid];
#pragma unroll
  for (int off = 32; off > 0; off >>= 1) v += __shfl_xor(v, off);
  __shared__ float red[4];
  const int w = tid >> 6, lane = tid & 63;
  if (lane == 0) red[w] = v;
  __syncthreads();
  if (tid == 0) {
    const float z = red[0] + red[1] + red[2] + red[3] + head_b[0];
    out[b] = 1.f / (1.f + __expf(-z));
  }
}

// =====================================================================
extern "C" void kernel_launch(void* const* d_in, const int* in_sizes, int n_in,
                              void* d_out, int out_size, void* d_ws, size_t ws_size,
                              hipStream_t stream) {
  (void)in_sizes; (void)n_in; (void)out_size; (void)ws_size;
  const float* src_pad = (const float*)d_in[0];
  const float* emb_w = (const float*)d_in[1];
  const float* emb_b = (const float*)d_in[2];
  const float* qkv_w = (const float*)d_in[3];
  const float* qkv_b = (const float*)d_in[4];
  const float* out_w = (const float*)d_in[5];
  const float* out_b = (const float*)d_in[6];
  const float* ff1_w = (const float*)d_in[7];
  const float* ff1_b = (const float*)d_in[8];
  const float* ff2_w = (const float*)d_in[9];
  const float* ff2_b = (const float*)d_in[10];
  const float* ln1_g = (const float*)d_in[11];
  const float* ln1_b = (const float*)d_in[12];
  const float* ln2_g = (const float*)d_in[13];
  const float* ln2_b = (const float*)d_in[14];
  const float* lat_w = (const float*)d_in[15];
  const float* lat_b = (const float*)d_in[16];
  const float* head_w = (const float*)d_in[17];
  const float* head_b = (const float*)d_in[18];
  float* out = (float*)d_out;

  // workspace layout (~180 MB)
  char* p = (char*)d_ws;
  unsigned short* xb = (unsigned short*)p; p += (size_t)16384 * 512 * 2;  // bf16 residual stream
  unsigned short* qkv = (unsigned short*)p; p += (size_t)16384 * 1536 * 2;
  unsigned short* attno = (unsigned short*)p; p += (size_t)16384 * 512 * 2;
  unsigned short* h = (unsigned short*)p;     p += (size_t)16384 * 2048 * 2;
  unsigned short* wq = (unsigned short*)p;    p += (size_t)4718592 * 2;
  unsigned short* wo = (unsigned short*)p;    p += (size_t)1572864 * 2;
  unsigned short* wf1 = (unsigned short*)p;   p += (size_t)6291456 * 2;
  unsigned short* wf2 = (unsigned short*)p;   p += (size_t)6291456 * 2;
  float* mem = (float*)p;           p += (size_t)16384 * 4;

  cvt_all_kernel<<<18432, 256, 0, stream>>>(qkv_w, wq, out_w, wo, ff1_w, wf1,
                                            ff2_w, wf2);

  embed_kernel<<<16384, 512, 0, stream>>>(src_pad, emb_w, emb_b, xb);

  for (int l = 0; l < 6; l++) {
    // QKV: M=16384, N=1536, K=512 -> 128x256 tiles, grid 768
    gemm_pipe<128, 0><<<dim3(128, 6), 512, 0, stream>>>(
        xb, wq + (size_t)l * 786432, qkv_b + (size_t)l * 1536, qkv,
        16384, 1536, 512);
    attn_fused<<<512, 256, 0, stream>>>(qkv, attno);
    // out-proj + residual + LN1 fused: grid 256 (64-row blocks)
    gemm_ln<<<256, 512, 0, stream>>>(
        attno, wo + (size_t)l * 262144, out_b + (size_t)l * 512,
        ln1_g + (size_t)l * 512, ln1_b + (size_t)l * 512, xb, 512);
    // FF1 (+relu): N=2048 -> 128x256 tiles, grid 1024
    gemm_pipe<128, 1><<<dim3(128, 8), 512, 0, stream>>>(
        xb, wf1 + (size_t)l * 1048576, ff1_b + (size_t)l * 2048, h,
        16384, 2048, 512);
    // FF2 + residual + LN2 fused: grid 256, K=2048
    gemm_ln<<<256, 512, 0, stream>>>(
        h, wf2 + (size_t)l * 1048576, ff2_b + (size_t)l * 512,
        ln2_g + (size_t)l * 512, ln2_b + (size_t)l * 512, xb, 2048);
  }

  zero_kernel<<<64, 256, 0, stream>>>(mem);
  latent_gemm<<<dim3(4, 128), 256, 0, stream>>>(xb, lat_w, mem);
  head_kernel<<<64, 256, 0, stream>>>(mem, lat_b, head_w, head_b, out);
}

// Round 17
// 1511.375 us; speedup vs baseline: 1.0304x; 1.0304x over previous
//
#include <hip/hip_runtime.h>
#include <hip/hip_bf16.h>
#include <cstdint>

#define DEV static __device__ __forceinline__

typedef __attribute__((ext_vector_type(8))) short bf16x8;
typedef __attribute__((ext_vector_type(4))) float f32x4;

// ---------- bf16 helpers (bit-level) ----------
DEV unsigned short f2bf(float f) {
  union { float f; unsigned u; } c; c.f = f;
  unsigned u = c.u;
  return (unsigned short)((u + 0x7fffu + ((u >> 16) & 1u)) >> 16);  // RNE
}
DEV float bf2f(unsigned short h) {
  union { unsigned u; float f; } c; c.u = ((unsigned)h) << 16; return c.f;
}
DEV float bflo(unsigned u) { union { unsigned u; float f; } c; c.u = u << 16; return c.f; }
DEV float bfhi(unsigned u) { union { unsigned u; float f; } c; c.u = u & 0xffff0000u; return c.f; }
// fast round-half-up bf16 pair pack: lo16 = bf(a), hi16 = bf(b), 3 VALU ops
DEV unsigned pack_bf16(float a, float b) {
  union { float f; unsigned u; } ca, cb; ca.f = a; cb.f = b;
  return __builtin_amdgcn_perm(cb.u + 0x8000u, ca.u + 0x8000u, 0x07060302u);
}

// async global->LDS, 16B per lane; LDS dest is wave-uniform base + lane*16
#define ASYNC_COPY16(gsrc, ldst)                                                      \
  __builtin_amdgcn_global_load_lds(                                                   \
      (const __attribute__((address_space(1))) void*)(unsigned long long)(gsrc),      \
      (__attribute__((address_space(3))) void*)(unsigned int)(unsigned long long)(ldst), \
      16, 0, 0)

// =====================================================================
// fp32 -> bf16 weight conversion, all four weight tensors in ONE launch
// (ranges: qkv 4608 blocks, out 1536, ff1 6144, ff2 6144 -> 18432)
// =====================================================================
__global__ void cvt_all_kernel(const float* __restrict__ s0, unsigned short* __restrict__ d0,
                               const float* __restrict__ s1, unsigned short* __restrict__ d1,
                               const float* __restrict__ s2, unsigned short* __restrict__ d2,
                               const float* __restrict__ s3, unsigned short* __restrict__ d3) {
  const int blk = blockIdx.x;
  const float* s; unsigned short* d; int base;
  if (blk < 4608)       { s = s0; d = d0; base = blk; }
  else if (blk < 6144)  { s = s1; d = d1; base = blk - 4608; }
  else if (blk < 12288) { s = s2; d = d2; base = blk - 6144; }
  else                  { s = s3; d = d3; base = blk - 12288; }
  size_t i = ((size_t)base * 256 + threadIdx.x) * 4;
  float4 v = *(const float4*)(s + i);
  d[i + 0] = f2bf(v.x);
  d[i + 1] = f2bf(v.y);
  d[i + 2] = f2bf(v.z);
  d[i + 3] = f2bf(v.w);
}

// =====================================================================
// embedding + positional encoding -> xb bf16 (residual stream is bf16)
// =====================================================================
__global__ void embed_kernel(const float* __restrict__ src,    // [B*S,16]
                             const float* __restrict__ emb_w,  // [512,16]
                             const float* __restrict__ emb_b,  // [512]
                             unsigned short* __restrict__ xb) {
  const int bs = blockIdx.x;        // 0..16383
  const int d = threadIdx.x;        // 0..511
  const int s = bs & 255;
  __shared__ float sv[16];
  if (d < 16) sv[d] = src[(size_t)bs * 16 + d];
  __syncthreads();
  const float* wr = emb_w + (size_t)d * 16;
  float acc = emb_b[d];
#pragma unroll
  for (int v = 0; v < 16; v++) acc += sv[v] * wr[v];
  const float den = __expf(-(float)(d & ~1) * (9.2103403719761836f / 512.f));
  const float arg = (float)s * den;
  acc += (d & 1) ? __cosf(arg) : __sinf(arg);
  xb[(size_t)bs * 512 + d] = f2bf(acc);
}

// =====================================================================
// Depth-2 pipelined bf16 MFMA GEMM, NT: C = A.B^T + bias (+relu).
// BM=128, BN=256, BK=64, 512 thr = 8 waves (2M x 4N), wave tile 64x64.
// THREE LDS buffers rotate; counted vmcnt(6); ONE barrier per K-tile.
// [r13 measured-best version, reverted from r15's phase experiment:
//  4 GEMM-schedule variants (r4/r8/r15 vs baseline) all land ~600 TF at
//  this tile/occupancy -> interior scheduling exhausted.]
// =====================================================================
template <int BM, int RELU>
__global__ __launch_bounds__(512, 2) void gemm_pipe(
    const unsigned short* __restrict__ A,   // [M,K] bf16 activations
    const unsigned short* __restrict__ B,   // [N,K] bf16 weights
    const float* __restrict__ bias,         // [N]
    unsigned short* __restrict__ Cb,        // [M,N] bf16 out
    int M, int N, int K) {
  constexpr int BN = 256;
  constexpr int MT = BM / 32;        // 4 m-frags per wave
  constexpr int NT = 4;              // 4 n-frags per wave
  constexpr int NLA = BM / 64;       // 2 A-chunk loads per K-tile
  constexpr int NL = NLA + BN / 64;  // + 4 B-chunks = 6 loads per K-tile
  constexpr int BUFE = (BM + BN) * 64;  // 24576 elems = 48KB per buffer
  __shared__ unsigned short lds[3 * BUFE];  // 144KB, 1 block/CU

  const int tid = threadIdx.x;
  const int lane = tid & 63;
  const int w = tid >> 6;      // 0..7
  const int wmi = w >> 2;      // 0..1
  const int wni = w & 3;       // 0..3
  const int r16 = lane & 15;
  const int quad = lane >> 4;
  const int rsw = r16 & 7;
  const int m0 = blockIdx.x * BM;   // m fast -> XCD locality for A
  const int n0 = blockIdx.y * BN;

  const int srow = tid >> 3;
  const int scol = ((tid & 7) ^ (srow & 7)) * 8;
  const unsigned short* gA = A + (size_t)(m0 + srow) * K + scol;
  const unsigned short* gB = B + (size_t)(n0 + srow) * K + scol;

#define STG(i, bufi, kc)                                                        \
  do {                                                                          \
    if ((i) < NLA)                                                              \
      ASYNC_COPY16(gA + (size_t)((i) * 64) * K + (kc),                          \
                   lds + (bufi) * BUFE + ((i) * 64 + w * 8) * 64);              \
    else                                                                        \
      ASYNC_COPY16(gB + (size_t)(((i) - NLA) * 64) * K + (kc),                  \
                   lds + (bufi) * BUFE + (BM + ((i) - NLA) * 64 + w * 8) * 64); \
  } while (0)

  f32x4 acc[MT][NT] = {};  // acc[i][j]: D[n=quad*4+r][m=r16]

  const int NK = K >> 6;
  // prologue: stage tiles 0 and 1 (12 loads in flight)
#pragma unroll
  for (int i = 0; i < NL; ++i) STG(i, 0, 0);
#pragma unroll
  for (int i = 0; i < NL; ++i) STG(i, 1, 64);

  for (int kt = 0; kt < NK; ++kt) {
    const int buf = kt % 3;
    // wait for tile kt's loads only (tile kt+1's NL loads stay in flight)
    if (kt + 1 < NK)
      asm volatile("s_waitcnt vmcnt(%0)" ::"i"(NL) : "memory");
    else
      asm volatile("s_waitcnt vmcnt(0)" ::: "memory");
    __builtin_amdgcn_s_barrier();
    // stage tile kt+2 into the buffer whose reads (tile kt-1) are done
    if (kt + 2 < NK) {
      const int sb = (kt + 2) % 3;
      const int kc = (kt + 2) << 6;
#pragma unroll
      for (int i = 0; i < NL; ++i) STG(i, sb, kc);
    }
    const unsigned short* As = lds + buf * BUFE;
    const unsigned short* Bs = As + BM * 64;
#pragma unroll
    for (int kh = 0; kh < 2; ++kh) {
      const int ko = ((kh * 4 + quad) ^ rsw) * 8;
      bf16x8 aR[MT], bR[NT];
#pragma unroll
      for (int m = 0; m < MT; ++m)
        aR[m] = *(const bf16x8*)(As + (wmi * 64 + m * 16 + r16) * 64 + ko);
#pragma unroll
      for (int j = 0; j < NT; ++j)
        bR[j] = *(const bf16x8*)(Bs + (wni * 64 + j * 16 + r16) * 64 + ko);
      __builtin_amdgcn_s_setprio(1);
#pragma unroll
      for (int m = 0; m < MT; ++m)
#pragma unroll
        for (int j = 0; j < NT; ++j)
          acc[m][j] = __builtin_amdgcn_mfma_f32_16x16x32_bf16(
              bR[j], aR[m], acc[m][j], 0, 0, 0);
      __builtin_amdgcn_s_setprio(0);
    }
    // all our ds_reads of buf done before we can pass the next barrier
    asm volatile("s_waitcnt lgkmcnt(0)" ::: "memory");
  }
#undef STG

  const int mb = m0 + wmi * 64 + r16;
  const int nb = n0 + wni * 64 + quad * 4;
#pragma unroll
  for (int j = 0; j < NT; ++j) {
    const int n = nb + j * 16;
    const float4 bv = *(const float4*)(bias + n);
#pragma unroll
    for (int i = 0; i < MT; ++i) {
      const size_t off = (size_t)(mb + i * 16) * N + n;
      float4 v;
      v.x = acc[i][j][0] + bv.x;
      v.y = acc[i][j][1] + bv.y;
      v.z = acc[i][j][2] + bv.z;
      v.w = acc[i][j][3] + bv.w;
      if (RELU) {
        v.x = fmaxf(v.x, 0.f); v.y = fmaxf(v.y, 0.f);
        v.z = fmaxf(v.z, 0.f); v.w = fmaxf(v.w, 0.f);
      }
      uint2 u;
      u.x = pack_bf16(v.x, v.y);
      u.y = pack_bf16(v.z, v.w);
      *(uint2*)(Cb + off) = u;
    }
  }
}

// =====================================================================
// GEMM + residual + LayerNorm fused (for the two N=512 projections):
// xb[m][:] = LN(A.B^T + bias + xb)[m][:] * g + beta, bf16 out in place.
// BM=64, BN=512, BK=64, 512 thr = 8 waves (wave w owns cols w*64..+63,
// all 64 rows).  A block owns FULL rows -> LN in epilogue.
// [round-13 measured win — unchanged]
// =====================================================================
__global__ __launch_bounds__(512, 2) void gemm_ln(
    const unsigned short* __restrict__ A,    // [M,K] bf16
    const unsigned short* __restrict__ B,    // [512,K] bf16 weights
    const float* __restrict__ bias,          // [512]
    const float* __restrict__ g,             // [512] ln gamma
    const float* __restrict__ beta,          // [512] ln beta
    unsigned short* __restrict__ xb,         // [M,512] residual in / out
    int K) {
  constexpr int BM = 64;
  constexpr int MT = 4;                 // 4 m-frags (rows i*16+r16)
  constexpr int NT = 4;                 // 4 n-frags per wave (64 cols)
  constexpr int NL = 1 + 8;             // 1 A-chunk + 8 B-chunks per K-tile
  constexpr int BUFE = (BM + 512) * 64; // 36864 elems = 72KB per buffer
  __shared__ unsigned short lds[2 * BUFE];  // 147456 B

  const int tid = threadIdx.x;
  const int lane = tid & 63;
  const int w = tid >> 6;     // 0..7: wave's col block = w*64
  const int r16 = lane & 15;
  const int quad = lane >> 4;
  const int rsw = r16 & 7;
  const int m0 = blockIdx.x * BM;

  const int srow = tid >> 3;
  const int scol = ((tid & 7) ^ (srow & 7)) * 8;
  const unsigned short* gA = A + (size_t)(m0 + srow) * K + scol;
  const unsigned short* gB = B + (size_t)srow * K + scol;

#define STG2(i, bufi, kc)                                                       \
  do {                                                                          \
    if ((i) == 0)                                                               \
      ASYNC_COPY16(gA + (size_t)(kc), lds + (bufi) * BUFE + (w * 8) * 64);      \
    else                                                                        \
      ASYNC_COPY16(gB + (size_t)(((i) - 1) * 64) * K + (kc),                    \
                   lds + (bufi) * BUFE + (BM + ((i) - 1) * 64 + w * 8) * 64);   \
  } while (0)

  f32x4 acc[MT][NT] = {};  // acc[i][j]: D[n=quad*4+r][m=r16]

  const int NK = K >> 6;
  // prologue: stage tile 0 -> buf 0
#pragma unroll
  for (int i = 0; i < NL; ++i) STG2(i, 0, 0);

  for (int kt = 0; kt < NK; ++kt) {
    const int buf = kt & 1;
    // stage kt+1 into buf^1 (freed by previous iter's trailing barrier)
    if (kt + 1 < NK) {
      const int kc = (kt + 1) << 6;
#pragma unroll
      for (int i = 0; i < NL; ++i) STG2(i, buf ^ 1, kc);
      asm volatile("s_waitcnt vmcnt(%0)" ::"i"(NL) : "memory");  // tile kt landed
    } else {
      asm volatile("s_waitcnt vmcnt(0)" ::: "memory");
    }
    __builtin_amdgcn_s_barrier();  // all waves' tile-kt loads landed
    const unsigned short* As = lds + buf * BUFE;
    const unsigned short* Bs = As + BM * 64;
#pragma unroll
    for (int kh = 0; kh < 2; ++kh) {
      const int ko = ((kh * 4 + quad) ^ rsw) * 8;
      bf16x8 aR[MT], bR[NT];
#pragma unroll
      for (int m = 0; m < MT; ++m)
        aR[m] = *(const bf16x8*)(As + (m * 16 + r16) * 64 + ko);
#pragma unroll
      for (int j = 0; j < NT; ++j)
        bR[j] = *(const bf16x8*)(Bs + (w * 64 + j * 16 + r16) * 64 + ko);
      __builtin_amdgcn_s_setprio(1);
#pragma unroll
      for (int m = 0; m < MT; ++m)
#pragma unroll
        for (int j = 0; j < NT; ++j)
          acc[m][j] = __builtin_amdgcn_mfma_f32_16x16x32_bf16(
              bR[j], aR[m], acc[m][j], 0, 0, 0);
      __builtin_amdgcn_s_setprio(0);
    }
    // all our ds_reads of buf done; barrier frees buf for the next restage
    asm volatile("s_waitcnt lgkmcnt(0)" ::: "memory");
    __builtin_amdgcn_s_barrier();
  }
#undef STG2

  // ---- epilogue: z = acc + bias + res; row LN; write xb bf16 ----
  // lane holds rows m = i*16+r16 (i=0..3), cols n = w*64 + j*16 + quad*4 + r
  const int nb = w * 64 + quad * 4;
  float psum[MT] = {}, psq[MT] = {};
#pragma unroll
  for (int j = 0; j < NT; ++j) {
    const int n = nb + j * 16;
    const float4 bv = *(const float4*)(bias + n);
#pragma unroll
    for (int i = 0; i < MT; ++i) {
      const size_t off = (size_t)(m0 + i * 16 + r16) * 512 + n;
      const uint2 ru = *(const uint2*)(xb + off);
      f32x4 v;
      v[0] = acc[i][j][0] + bv.x + bflo(ru.x);
      v[1] = acc[i][j][1] + bv.y + bfhi(ru.x);
      v[2] = acc[i][j][2] + bv.z + bflo(ru.y);
      v[3] = acc[i][j][3] + bv.w + bfhi(ru.y);
      acc[i][j] = v;  // keep z in regs
#pragma unroll
      for (int r = 0; r < 4; ++r) {
        psum[i] += v[r];
        psq[i] += v[r] * v[r];
      }
    }
  }
  // quad-reduce (lanes quad*16+r16 share a row set)
#pragma unroll
  for (int i = 0; i < MT; ++i) {
    psum[i] += __shfl_xor(psum[i], 16);
    psum[i] += __shfl_xor(psum[i], 32);
    psq[i] += __shfl_xor(psq[i], 16);
    psq[i] += __shfl_xor(psq[i], 32);
  }
  // cross-wave via LDS (staging buffers are dead: trailing barrier passed)
  float* redS = (float*)lds;          // [8][64]
  float* redQ = redS + 512;           // [8][64]
  if (quad == 0) {
#pragma unroll
    for (int i = 0; i < MT; ++i) {
      redS[w * 64 + i * 16 + r16] = psum[i];
      redQ[w * 64 + i * 16 + r16] = psq[i];
    }
  }
  __syncthreads();
  float mu[MT], rs[MT];
#pragma unroll
  for (int i = 0; i < MT; ++i) {
    const int row = i * 16 + r16;
    float s = 0.f, q = 0.f;
#pragma unroll
    for (int ww = 0; ww < 8; ++ww) {
      s += redS[ww * 64 + row];
      q += redQ[ww * 64 + row];
    }
    mu[i] = s * (1.f / 512.f);
    rs[i] = rsqrtf(q * (1.f / 512.f) - mu[i] * mu[i] + 1e-5f);
  }
#pragma unroll
  for (int j = 0; j < NT; ++j) {
    const int n = nb + j * 16;
    const float4 gv = *(const float4*)(g + n);
    const float4 be = *(const float4*)(beta + n);
#pragma unroll
    for (int i = 0; i < MT; ++i) {
      const size_t off = (size_t)(m0 + i * 16 + r16) * 512 + n;
      const f32x4 v = acc[i][j];
      float o0 = (v[0] - mu[i]) * rs[i] * gv.x + be.x;
      float o1 = (v[1] - mu[i]) * rs[i] * gv.y + be.y;
      float o2 = (v[2] - mu[i]) * rs[i] * gv.z + be.z;
      float o3 = (v[3] - mu[i]) * rs[i] * gv.w + be.w;
      uint2 u;
      u.x = pack_bf16(o0, o1);
      u.y = pack_bf16(o2, o3);
      *(uint2*)(xb + off) = u;
    }
  }
}

// =====================================================================
// Fused attention: one block per (b,h). V^T staged once (33.8KB);
// loop over 8 q-tiles of 32: S^T scores (wave = k-quarter, A=K, B=Q from
// global), MERGED one-round softmax (flash-style): each wave writes its
// local (max m_w, sum-of-exp s_w) pair, ONE barrier, lanes combine
// m_g = max_w m_w, s_g = sum_w s_w*exp((m_w-m_g)/8) and fold their own
// wave's correction exp((m_l-m_g)/8)/s_g into the P scale.  Barriers
// per q-tile: 3 -> 2.  Numerically = exact softmax up to fp32 exp
// factorization rounding.  P packed to LDS (stride 264), PV = Vt.P.
// =====================================================================
__global__ __launch_bounds__(256, 2) void attn_fused(
    const unsigned short* __restrict__ qkv,  // [B*S,1536] bf16 q|k|v
    unsigned short* __restrict__ O) {        // [B*S,512] bf16
  __shared__ unsigned short Vt[64 * 264];  // V^T[d][k], stride 264
  __shared__ unsigned short Pl[32 * 264];  // P[q][k],  stride 264
  __shared__ float redM[4][32];
  __shared__ float redS[4][32];
  const int tid = threadIdx.x;
  const int lane = tid & 63;
  const int w = tid >> 6;
  const int r16 = lane & 15;
  const int quad = lane >> 4;
  const int h = blockIdx.x & 7;
  const int b = blockIdx.x >> 3;

  // stage V^T (verified round-2 pattern)
  {
    const int kp = w * 32 + (lane & 31);
    const int dhalf = lane >> 5;
    const unsigned short* vbase =
        qkv + (size_t)(b * 256 + 2 * kp) * 1536 + 1024 + h * 64;
    unsigned* dst = (unsigned*)Vt;
#pragma unroll
    for (int t = 0; t < 4; t++) {
      const int dc = dhalf + 2 * t;  // d-chunk 0..7
      const uint4 a = *(const uint4*)(vbase + dc * 8);
      const uint4 bb = *(const uint4*)(vbase + 1536 + dc * 8);
      const unsigned* ap = (const unsigned*)&a;
      const unsigned* bp = (const unsigned*)&bb;
#pragma unroll
      for (int i = 0; i < 4; i++) {
        const unsigned lo = ap[i], hi = bp[i];
        dst[(dc * 8 + 2 * i) * 132 + kp] = (lo & 0xffffu) | (hi << 16);
        dst[(dc * 8 + 2 * i + 1) * 132 + kp] = (lo >> 16) | (hi & 0xffff0000u);
      }
    }
  }
  __syncthreads();

  const unsigned short* krow =
      qkv + (size_t)(b * 256 + r16) * 1536 + 512 + h * 64 + quad * 8;
  const unsigned short* qrow =
      qkv + (size_t)(b * 256 + r16) * 1536 + h * 64 + quad * 8;

  for (int qt = 0; qt < 8; qt++) {
    const int q0 = qt * 32;
    f32x4 acc[4][2] = {};  // acc[mt][nt]: S^T[k=w*64+mt*16+quad*4+r][q=q0+nt*16+r16]
    bf16x8 bQ0[2], bQ1[2];
#pragma unroll
    for (int nt = 0; nt < 2; nt++) {
      const unsigned short* qp = qrow + (size_t)(q0 + nt * 16) * 1536;
      bQ0[nt] = *(const bf16x8*)(qp);
      bQ1[nt] = *(const bf16x8*)(qp + 32);
    }
#pragma unroll
    for (int mt = 0; mt < 4; mt++) {
      const unsigned short* kp = krow + (size_t)(w * 64 + mt * 16) * 1536;
      const bf16x8 aK0 = *(const bf16x8*)(kp);
      const bf16x8 aK1 = *(const bf16x8*)(kp + 32);
#pragma unroll
      for (int nt = 0; nt < 2; nt++) {
        acc[mt][nt] = __builtin_amdgcn_mfma_f32_16x16x32_bf16(aK0, bQ0[nt], acc[mt][nt], 0, 0, 0);
        acc[mt][nt] = __builtin_amdgcn_mfma_f32_16x16x32_bf16(aK1, bQ1[nt], acc[mt][nt], 0, 0, 0);
      }
    }
    // ---- merged softmax: local max + local sum, ONE cross-wave round
    float ml[2];
#pragma unroll
    for (int nt = 0; nt < 2; nt++) {
      float m = acc[0][nt][0];
#pragma unroll
      for (int mt = 0; mt < 4; mt++)
#pragma unroll
        for (int r = 0; r < 4; r++) m = fmaxf(m, acc[mt][nt][r]);
      m = fmaxf(m, __shfl_xor(m, 16));
      m = fmaxf(m, __shfl_xor(m, 32));
      ml[nt] = m;
      float s = 0.f;
#pragma unroll
      for (int mt = 0; mt < 4; mt++)
#pragma unroll
        for (int r = 0; r < 4; r++) {
          acc[mt][nt][r] = __expf((acc[mt][nt][r] - m) * 0.125f);
          s += acc[mt][nt][r];
        }
      s += __shfl_xor(s, 16);
      s += __shfl_xor(s, 32);
      if (quad == 0) {
        redM[w][nt * 16 + r16] = m;
        redS[w][nt * 16 + r16] = s;
      }
    }
    __syncthreads();
    float scale[2];
#pragma unroll
    for (int nt = 0; nt < 2; nt++) {
      const int q = nt * 16 + r16;
      const float m0_ = redM[0][q], m1_ = redM[1][q];
      const float m2_ = redM[2][q], m3_ = redM[3][q];
      const float mg = fmaxf(fmaxf(m0_, m1_), fmaxf(m2_, m3_));
      const float sg = redS[0][q] * __expf((m0_ - mg) * 0.125f) +
                       redS[1][q] * __expf((m1_ - mg) * 0.125f) +
                       redS[2][q] * __expf((m2_ - mg) * 0.125f) +
                       redS[3][q] * __expf((m3_ - mg) * 0.125f);
      scale[nt] = __expf((ml[nt] - mg) * 0.125f) / sg;
    }
#pragma unroll
    for (int nt = 0; nt < 2; nt++) {
      unsigned short* prow = Pl + (nt * 16 + r16) * 264 + w * 64 + quad * 4;
#pragma unroll
      for (int mt = 0; mt < 4; mt++) {
        uint2 u;
        u.x = pack_bf16(acc[mt][nt][0] * scale[nt], acc[mt][nt][1] * scale[nt]);
        u.y = pack_bf16(acc[mt][nt][2] * scale[nt], acc[mt][nt][3] * scale[nt]);
        *(uint2*)(prow + mt * 16) = u;
      }
    }
    __syncthreads();
    f32x4 o[2] = {};
#pragma unroll
    for (int s = 0; s < 8; s++) {
      const bf16x8 aV = *(const bf16x8*)(Vt + (w * 16 + r16) * 264 + s * 32 + quad * 8);
#pragma unroll
      for (int nt = 0; nt < 2; nt++) {
        const bf16x8 bP = *(const bf16x8*)(Pl + (nt * 16 + r16) * 264 + s * 32 + quad * 8);
        o[nt] = __builtin_amdgcn_mfma_f32_16x16x32_bf16(aV, bP, o[nt], 0, 0, 0);
      }
    }
#pragma unroll
    for (int nt = 0; nt < 2; nt++) {
      uint2 u;
      u.x = pack_bf16(o[nt][0], o[nt][1]);
      u.y = pack_bf16(o[nt][2], o[nt][3]);
      *(uint2*)(O + (size_t)(b * 256 + q0 + nt * 16 + r16) * 512 + h * 64 +
                w * 16 + quad * 4) = u;
    }
  }
}

// =====================================================================
// latent: mem[64,256] += xb[64,131072](bf16) . W[256,131072]^T
// bf16 MFMA streaming, W converted fp32->bf16 in-flight, split-K atomics.
// =====================================================================
__global__ void zero_kernel(float* __restrict__ p) {
  p[blockIdx.x * 256 + threadIdx.x] = 0.f;
}

__global__ __launch_bounds__(256) void latent_gemm(
    const unsigned short* __restrict__ xb, const float* __restrict__ W,
    float* __restrict__ mem) {
  const int tid = threadIdx.x;
  const int lane = tid & 63;
  const int w = tid >> 6;
  const int r16 = lane & 15;
  const int quad = lane >> 4;
  const int n0 = blockIdx.x * 64 + w * 16;     // wave's 16 n-rows
  const int kc0 = blockIdx.y * 1024;

  const float* wrow = W + (size_t)(n0 + r16) * 131072 + kc0 + quad * 8;
  const unsigned short* xrow = xb + (size_t)r16 * 131072 + kc0 + quad * 8;

  f32x4 c[4] = {};  // C[b = i*16+quad*4+reg][n = n0+r16]
  for (int k = 0; k < 1024; k += 32) {
    const float4 wa = *(const float4*)(wrow + k);
    const float4 wb = *(const float4*)(wrow + k + 4);
    union { unsigned u[4]; bf16x8 v; } cw;
    cw.u[0] = pack_bf16(wa.x, wa.y);
    cw.u[1] = pack_bf16(wa.z, wa.w);
    cw.u[2] = pack_bf16(wb.x, wb.y);
    cw.u[3] = pack_bf16(wb.z, wb.w);
#pragma unroll
    for (int i = 0; i < 4; i++) {
      const bf16x8 aX = *(const bf16x8*)(xrow + (size_t)i * 2097152 + k);
      c[i] = __builtin_amdgcn_mfma_f32_16x16x32_bf16(aX, cw.v, c[i], 0, 0, 0);
    }
  }
#pragma unroll
  for (int i = 0; i < 4; i++)
#pragma unroll
    for (int r = 0; r < 4; r++)
      atomicAdd(&mem[(size_t)(i * 16 + quad * 4 + r) * 256 + n0 + r16], c[i][r]);
}

// =====================================================================
__global__ __launch_bounds__(256) void head_kernel(
    const float* __restrict__ mem, const float* __restrict__ lat_b,
    const float* __restrict__ head_w, const float* __restrict__ head_b,
    float* __restrict__ out) {
  const int b = blockIdx.x;
  const int tid = threadIdx.x;
  float v = (mem[(size_t)b * 256 + tid] + lat_b[tid]) * head_w[tid];
#pragma unroll
  for (int off = 32; off > 0; off >>= 1) v += __shfl_xor(v, off);
  __shared__ float red[4];
  const int w = tid >> 6, lane = tid & 63;
  if (lane == 0) red[w] = v;
  __syncthreads();
  if (tid == 0) {
    const float z = red[0] + red[1] + red[2] + red[3] + head_b[0];
    out[b] = 1.f / (1.f + __expf(-z));
  }
}

// =====================================================================
extern "C" void kernel_launch(void* const* d_in, const int* in_sizes, int n_in,
                              void* d_out, int out_size, void* d_ws, size_t ws_size,
                              hipStream_t stream) {
  (void)in_sizes; (void)n_in; (void)out_size; (void)ws_size;
  const float* src_pad = (const float*)d_in[0];
  const float* emb_w = (const float*)d_in[1];
  const float* emb_b = (const float*)d_in[2];
  const float* qkv_w = (const float*)d_in[3];
  const float* qkv_b = (const float*)d_in[4];
  const float* out_w = (const float*)d_in[5];
  const float* out_b = (const float*)d_in[6];
  const float* ff1_w = (const float*)d_in[7];
  const float* ff1_b = (const float*)d_in[8];
  const float* ff2_w = (const float*)d_in[9];
  const float* ff2_b = (const float*)d_in[10];
  const float* ln1_g = (const float*)d_in[11];
  const float* ln1_b = (const float*)d_in[12];
  const float* ln2_g = (const float*)d_in[13];
  const float* ln2_b = (const float*)d_in[14];
  const float* lat_w = (const float*)d_in[15];
  const float* lat_b = (const float*)d_in[16];
  const float* head_w = (const float*)d_in[17];
  const float* head_b = (const float*)d_in[18];
  float* out = (float*)d_out;

  // workspace layout (~180 MB)
  char* p = (char*)d_ws;
  unsigned short* xb = (unsigned short*)p; p += (size_t)16384 * 512 * 2;  // bf16 residual stream
  unsigned short* qkv = (unsigned short*)p; p += (size_t)16384 * 1536 * 2;
  unsigned short* attno = (unsigned short*)p; p += (size_t)16384 * 512 * 2;
  unsigned short* h = (unsigned short*)p;     p += (size_t)16384 * 2048 * 2;
  unsigned short* wq = (unsigned short*)p;    p += (size_t)4718592 * 2;
  unsigned short* wo = (unsigned short*)p;    p += (size_t)1572864 * 2;
  unsigned short* wf1 = (unsigned short*)p;   p += (size_t)6291456 * 2;
  unsigned short* wf2 = (unsigned short*)p;   p += (size_t)6291456 * 2;
  float* mem = (float*)p;           p += (size_t)16384 * 4;

  cvt_all_kernel<<<18432, 256, 0, stream>>>(qkv_w, wq, out_w, wo, ff1_w, wf1,
                                            ff2_w, wf2);

  embed_kernel<<<16384, 512, 0, stream>>>(src_pad, emb_w, emb_b, xb);

  for (int l = 0; l < 6; l++) {
    // QKV: M=16384, N=1536, K=512 -> 128x256 tiles, grid 768
    gemm_pipe<128, 0><<<dim3(128, 6), 512, 0, stream>>>(
        xb, wq + (size_t)l * 786432, qkv_b + (size_t)l * 1536, qkv,
        16384, 1536, 512);
    attn_fused<<<512, 256, 0, stream>>>(qkv, attno);
    // out-proj + residual + LN1 fused: grid 256 (64-row blocks)
    gemm_ln<<<256, 512, 0, stream>>>(
        attno, wo + (size_t)l * 262144, out_b + (size_t)l * 512,
        ln1_g + (size_t)l * 512, ln1_b + (size_t)l * 512, xb, 512);
    // FF1 (+relu): N=2048 -> 128x256 tiles, grid 1024
    gemm_pipe<128, 1><<<dim3(128, 8), 512, 0, stream>>>(
        xb, wf1 + (size_t)l * 1048576, ff1_b + (size_t)l * 2048, h,
        16384, 2048, 512);
    // FF2 + residual + LN2 fused: grid 256, K=2048
    gemm_ln<<<256, 512, 0, stream>>>(
        h, wf2 + (size_t)l * 1048576, ff2_b + (size_t)l * 512,
        ln2_g + (size_t)l * 512, ln2_b + (size_t)l * 512, xb, 2048);
  }

  zero_kernel<<<64, 256, 0, stream>>>(mem);
  latent_gemm<<<dim3(4, 128), 256, 0, stream>>>(xb, lat_w, mem);
  head_kernel<<<64, 256, 0, stream>>>(mem, lat_b, head_w, head_b, out);
}

// Round 18
// 1476.914 us; speedup vs baseline: 1.0544x; 1.0233x over previous
//
#include <hip/hip_runtime.h>
#include <hip/hip_bf16.h>
#include <cstdint>

#define DEV static __device__ __forceinline__

typedef __attribute__((ext_vector_type(8))) short bf16x8;
typedef __attribute__((ext_vector_type(4))) float f32x4;

// ---------- bf16 helpers (bit-level) ----------
DEV unsigned short f2bf(float f) {
  union { float f; unsigned u; } c; c.f = f;
  unsigned u = c.u;
  return (unsigned short)((u + 0x7fffu + ((u >> 16) & 1u)) >> 16);  // RNE
}
DEV float bf2f(unsigned short h) {
  union { unsigned u; float f; } c; c.u = ((unsigned)h) << 16; return c.f;
}
DEV float bflo(unsigned u) { union { unsigned u; float f; } c; c.u = u << 16; return c.f; }
DEV float bfhi(unsigned u) { union { unsigned u; float f; } c; c.u = u & 0xffff0000u; return c.f; }
// fast round-half-up bf16 pair pack: lo16 = bf(a), hi16 = bf(b), 3 VALU ops
DEV unsigned pack_bf16(float a, float b) {
  union { float f; unsigned u; } ca, cb; ca.f = a; cb.f = b;
  return __builtin_amdgcn_perm(cb.u + 0x8000u, ca.u + 0x8000u, 0x07060302u);
}

// async global->LDS, 16B per lane; LDS dest is wave-uniform base + lane*16
#define ASYNC_COPY16(gsrc, ldst)                                                      \
  __builtin_amdgcn_global_load_lds(                                                   \
      (const __attribute__((address_space(1))) void*)(unsigned long long)(gsrc),      \
      (__attribute__((address_space(3))) void*)(unsigned int)(unsigned long long)(ldst), \
      16, 0, 0)

// =====================================================================
// fp32 -> bf16 weight conversion, all four weight tensors in ONE launch
// (ranges: qkv 4608 blocks, out 1536, ff1 6144, ff2 6144 -> 18432)
// =====================================================================
__global__ void cvt_all_kernel(const float* __restrict__ s0, unsigned short* __restrict__ d0,
                               const float* __restrict__ s1, unsigned short* __restrict__ d1,
                               const float* __restrict__ s2, unsigned short* __restrict__ d2,
                               const float* __restrict__ s3, unsigned short* __restrict__ d3) {
  const int blk = blockIdx.x;
  const float* s; unsigned short* d; int base;
  if (blk < 4608)       { s = s0; d = d0; base = blk; }
  else if (blk < 6144)  { s = s1; d = d1; base = blk - 4608; }
  else if (blk < 12288) { s = s2; d = d2; base = blk - 6144; }
  else                  { s = s3; d = d3; base = blk - 12288; }
  size_t i = ((size_t)base * 256 + threadIdx.x) * 4;
  float4 v = *(const float4*)(s + i);
  d[i + 0] = f2bf(v.x);
  d[i + 1] = f2bf(v.y);
  d[i + 2] = f2bf(v.z);
  d[i + 3] = f2bf(v.w);
}

// =====================================================================
// embedding + positional encoding -> xb bf16 (residual stream is bf16)
// =====================================================================
__global__ void embed_kernel(const float* __restrict__ src,    // [B*S,16]
                             const float* __restrict__ emb_w,  // [512,16]
                             const float* __restrict__ emb_b,  // [512]
                             unsigned short* __restrict__ xb) {
  const int bs = blockIdx.x;        // 0..16383
  const int d = threadIdx.x;        // 0..511
  const int s = bs & 255;
  __shared__ float sv[16];
  if (d < 16) sv[d] = src[(size_t)bs * 16 + d];
  __syncthreads();
  const float* wr = emb_w + (size_t)d * 16;
  float acc = emb_b[d];
#pragma unroll
  for (int v = 0; v < 16; v++) acc += sv[v] * wr[v];
  const float den = __expf(-(float)(d & ~1) * (9.2103403719761836f / 512.f));
  const float arg = (float)s * den;
  acc += (d & 1) ? __cosf(arg) : __sinf(arg);
  xb[(size_t)bs * 512 + d] = f2bf(acc);
}

// =====================================================================
// bf16 MFMA GEMM, NT (round-0 m97-style): C[m,n] = A.B^T + bias (+relu).
// BM=128, BN=128, BK=64, 256 thr = 4 waves (2x2), wave tile 64x64.
// SINGLE-buffered 32KB LDS -> 3 blocks/CU (launch_bounds(256,3)):
// co-resident blocks hide each other's barrier/load stalls (m114
// implicit wave-overlap) — the occupancy lever the 1-block/CU
// gemm_pipe lacks.  XOR chunk swizzle: slot s of row r holds global
// chunk s^(r&7); readers use (kh*4+quad)^(r16&7) -> conflict-free b128.
// Operands swapped (A_op = weights) so lane's 4 acc regs = 4 consec n.
// [round-0 harness-verified code, bit-identical accumulation order]
// =====================================================================
template <int RELU>
__global__ __launch_bounds__(256, 3) void gemm_nt(
    const unsigned short* __restrict__ A,   // [M,K] bf16 activations
    const unsigned short* __restrict__ B,   // [N,K] bf16 weights
    const float* __restrict__ bias,         // [N]
    unsigned short* __restrict__ Cb,        // [M,N] bf16 out
    int M, int N, int K) {
  constexpr int MT = 4;
  constexpr int NT = 4;
  __shared__ unsigned short As[128 * 64];
  __shared__ unsigned short Bs[128 * 64];
  const int tid = threadIdx.x;
  const int lane = tid & 63;
  const int w = tid >> 6;            // 0..3
  const int m0 = blockIdx.x * 128;   // m fast -> XCD locality for A
  const int n0 = blockIdx.y * 128;

  const int srow = lane >> 3;                  // 0..7
  const int scol = (((lane & 7) ^ srow)) * 8;  // swizzled chunk
  const unsigned short* gA0 = A + (size_t)(m0 + w * 32 + srow) * K + scol;
  unsigned short* lA0 = As + (w * 32) * 64;
  const unsigned short* gB0 = B + (size_t)(n0 + w * 32 + srow) * K + scol;
  unsigned short* lB0 = Bs + (w * 32) * 64;

  const int wm = (w >> 1) * 64;
  const int wn = (w & 1) * 64;
  const int r16 = lane & 15;
  const int quad = lane >> 4;
  const int rsw = r16 & 7;

  f32x4 acc[MT][NT] = {};  // acc[i][j]: D[n=quad*4+r][m=r16]

  for (int k0 = 0; k0 < K; k0 += 64) {
#pragma unroll
    for (int i = 0; i < 4; i++)
      ASYNC_COPY16(gA0 + (size_t)(i * 8) * K + k0, lA0 + i * 512);
#pragma unroll
    for (int i = 0; i < 4; i++)
      ASYNC_COPY16(gB0 + (size_t)(i * 8) * K + k0, lB0 + i * 512);
    asm volatile("s_waitcnt vmcnt(0)" ::: "memory");
    __syncthreads();
#pragma unroll
    for (int kh = 0; kh < 2; kh++) {
      const int ko = ((kh * 4 + quad) ^ rsw) * 8;
      bf16x8 xa[MT], wb[NT];
#pragma unroll
      for (int i = 0; i < MT; i++)
        xa[i] = *(const bf16x8*)(As + (wm + i * 16 + r16) * 64 + ko);
#pragma unroll
      for (int j = 0; j < NT; j++)
        wb[j] = *(const bf16x8*)(Bs + (wn + j * 16 + r16) * 64 + ko);
#pragma unroll
      for (int i = 0; i < MT; i++)
#pragma unroll
        for (int j = 0; j < NT; j++)
          acc[i][j] = __builtin_amdgcn_mfma_f32_16x16x32_bf16(wb[j], xa[i], acc[i][j], 0, 0, 0);
    }
    __syncthreads();
  }

  // epilogue: m = m0+wm+i*16+r16, n = n0+wn+j*16+quad*4 (+0..3)
  const int mb = m0 + wm + r16;
  const int nb = n0 + wn + quad * 4;
#pragma unroll
  for (int j = 0; j < NT; j++) {
    const int n = nb + j * 16;
    const float4 bv = *(const float4*)(bias + n);
#pragma unroll
    for (int i = 0; i < MT; i++) {
      const size_t off = (size_t)(mb + i * 16) * N + n;
      float4 v;
      v.x = acc[i][j][0] + bv.x;
      v.y = acc[i][j][1] + bv.y;
      v.z = acc[i][j][2] + bv.z;
      v.w = acc[i][j][3] + bv.w;
      if (RELU) {
        v.x = fmaxf(v.x, 0.f); v.y = fmaxf(v.y, 0.f);
        v.z = fmaxf(v.z, 0.f); v.w = fmaxf(v.w, 0.f);
      }
      uint2 u;
      u.x = pack_bf16(v.x, v.y);
      u.y = pack_bf16(v.z, v.w);
      *(uint2*)(Cb + off) = u;
    }
  }
}

// =====================================================================
// GEMM + residual + LayerNorm fused (for the two N=512 projections):
// xb[m][:] = LN(A.B^T + bias + xb)[m][:] * g + beta, bf16 out in place.
// BM=64, BN=512, BK=64, 512 thr = 8 waves (wave w owns cols w*64..+63,
// all 64 rows).  A block owns FULL rows -> LN in epilogue.
// [round-13 measured win — unchanged]
// =====================================================================
__global__ __launch_bounds__(512, 2) void gemm_ln(
    const unsigned short* __restrict__ A,    // [M,K] bf16
    const unsigned short* __restrict__ B,    // [512,K] bf16 weights
    const float* __restrict__ bias,          // [512]
    const float* __restrict__ g,             // [512] ln gamma
    const float* __restrict__ beta,          // [512] ln beta
    unsigned short* __restrict__ xb,         // [M,512] residual in / out
    int K) {
  constexpr int BM = 64;
  constexpr int MT = 4;                 // 4 m-frags (rows i*16+r16)
  constexpr int NT = 4;                 // 4 n-frags per wave (64 cols)
  constexpr int NL = 1 + 8;             // 1 A-chunk + 8 B-chunks per K-tile
  constexpr int BUFE = (BM + 512) * 64; // 36864 elems = 72KB per buffer
  __shared__ unsigned short lds[2 * BUFE];  // 147456 B

  const int tid = threadIdx.x;
  const int lane = tid & 63;
  const int w = tid >> 6;     // 0..7: wave's col block = w*64
  const int r16 = lane & 15;
  const int quad = lane >> 4;
  const int rsw = r16 & 7;
  const int m0 = blockIdx.x * BM;

  const int srow = tid >> 3;
  const int scol = ((tid & 7) ^ (srow & 7)) * 8;
  const unsigned short* gA = A + (size_t)(m0 + srow) * K + scol;
  const unsigned short* gB = B + (size_t)srow * K + scol;

#define STG2(i, bufi, kc)                                                       \
  do {                                                                          \
    if ((i) == 0)                                                               \
      ASYNC_COPY16(gA + (size_t)(kc), lds + (bufi) * BUFE + (w * 8) * 64);      \
    else                                                                        \
      ASYNC_COPY16(gB + (size_t)(((i) - 1) * 64) * K + (kc),                    \
                   lds + (bufi) * BUFE + (BM + ((i) - 1) * 64 + w * 8) * 64);   \
  } while (0)

  f32x4 acc[MT][NT] = {};  // acc[i][j]: D[n=quad*4+r][m=r16]

  const int NK = K >> 6;
  // prologue: stage tile 0 -> buf 0
#pragma unroll
  for (int i = 0; i < NL; ++i) STG2(i, 0, 0);

  for (int kt = 0; kt < NK; ++kt) {
    const int buf = kt & 1;
    // stage kt+1 into buf^1 (freed by previous iter's trailing barrier)
    if (kt + 1 < NK) {
      const int kc = (kt + 1) << 6;
#pragma unroll
      for (int i = 0; i < NL; ++i) STG2(i, buf ^ 1, kc);
      asm volatile("s_waitcnt vmcnt(%0)" ::"i"(NL) : "memory");  // tile kt landed
    } else {
      asm volatile("s_waitcnt vmcnt(0)" ::: "memory");
    }
    __builtin_amdgcn_s_barrier();  // all waves' tile-kt loads landed
    const unsigned short* As = lds + buf * BUFE;
    const unsigned short* Bs = As + BM * 64;
#pragma unroll
    for (int kh = 0; kh < 2; ++kh) {
      const int ko = ((kh * 4 + quad) ^ rsw) * 8;
      bf16x8 aR[MT], bR[NT];
#pragma unroll
      for (int m = 0; m < MT; ++m)
        aR[m] = *(const bf16x8*)(As + (m * 16 + r16) * 64 + ko);
#pragma unroll
      for (int j = 0; j < NT; ++j)
        bR[j] = *(const bf16x8*)(Bs + (w * 64 + j * 16 + r16) * 64 + ko);
      __builtin_amdgcn_s_setprio(1);
#pragma unroll
      for (int m = 0; m < MT; ++m)
#pragma unroll
        for (int j = 0; j < NT; ++j)
          acc[m][j] = __builtin_amdgcn_mfma_f32_16x16x32_bf16(
              bR[j], aR[m], acc[m][j], 0, 0, 0);
      __builtin_amdgcn_s_setprio(0);
    }
    // all our ds_reads of buf done; barrier frees buf for the next restage
    asm volatile("s_waitcnt lgkmcnt(0)" ::: "memory");
    __builtin_amdgcn_s_barrier();
  }
#undef STG2

  // ---- epilogue: z = acc + bias + res; row LN; write xb bf16 ----
  // lane holds rows m = i*16+r16 (i=0..3), cols n = w*64 + j*16 + quad*4 + r
  const int nb = w * 64 + quad * 4;
  float psum[MT] = {}, psq[MT] = {};
#pragma unroll
  for (int j = 0; j < NT; ++j) {
    const int n = nb + j * 16;
    const float4 bv = *(const float4*)(bias + n);
#pragma unroll
    for (int i = 0; i < MT; ++i) {
      const size_t off = (size_t)(m0 + i * 16 + r16) * 512 + n;
      const uint2 ru = *(const uint2*)(xb + off);
      f32x4 v;
      v[0] = acc[i][j][0] + bv.x + bflo(ru.x);
      v[1] = acc[i][j][1] + bv.y + bfhi(ru.x);
      v[2] = acc[i][j][2] + bv.z + bflo(ru.y);
      v[3] = acc[i][j][3] + bv.w + bfhi(ru.y);
      acc[i][j] = v;  // keep z in regs
#pragma unroll
      for (int r = 0; r < 4; ++r) {
        psum[i] += v[r];
        psq[i] += v[r] * v[r];
      }
    }
  }
  // quad-reduce (lanes quad*16+r16 share a row set)
#pragma unroll
  for (int i = 0; i < MT; ++i) {
    psum[i] += __shfl_xor(psum[i], 16);
    psum[i] += __shfl_xor(psum[i], 32);
    psq[i] += __shfl_xor(psq[i], 16);
    psq[i] += __shfl_xor(psq[i], 32);
  }
  // cross-wave via LDS (staging buffers are dead: trailing barrier passed)
  float* redS = (float*)lds;          // [8][64]
  float* redQ = redS + 512;           // [8][64]
  if (quad == 0) {
#pragma unroll
    for (int i = 0; i < MT; ++i) {
      redS[w * 64 + i * 16 + r16] = psum[i];
      redQ[w * 64 + i * 16 + r16] = psq[i];
    }
  }
  __syncthreads();
  float mu[MT], rs[MT];
#pragma unroll
  for (int i = 0; i < MT; ++i) {
    const int row = i * 16 + r16;
    float s = 0.f, q = 0.f;
#pragma unroll
    for (int ww = 0; ww < 8; ++ww) {
      s += redS[ww * 64 + row];
      q += redQ[ww * 64 + row];
    }
    mu[i] = s * (1.f / 512.f);
    rs[i] = rsqrtf(q * (1.f / 512.f) - mu[i] * mu[i] + 1e-5f);
  }
#pragma unroll
  for (int j = 0; j < NT; ++j) {
    const int n = nb + j * 16;
    const float4 gv = *(const float4*)(g + n);
    const float4 be = *(const float4*)(beta + n);
#pragma unroll
    for (int i = 0; i < MT; ++i) {
      const size_t off = (size_t)(m0 + i * 16 + r16) * 512 + n;
      const f32x4 v = acc[i][j];
      float o0 = (v[0] - mu[i]) * rs[i] * gv.x + be.x;
      float o1 = (v[1] - mu[i]) * rs[i] * gv.y + be.y;
      float o2 = (v[2] - mu[i]) * rs[i] * gv.z + be.z;
      float o3 = (v[3] - mu[i]) * rs[i] * gv.w + be.w;
      uint2 u;
      u.x = pack_bf16(o0, o1);
      u.y = pack_bf16(o2, o3);
      *(uint2*)(xb + off) = u;
    }
  }
}

// =====================================================================
// Fused attention: one block per (b,h). V^T staged once (33.8KB);
// loop over 8 q-tiles of 32: S^T scores (wave = k-quarter, A=K, B=Q from
// global), MERGED one-round softmax (flash-style).  Barriers/q-tile = 2
// (provably minimal for this dataflow).  [round-17 measured win]
// =====================================================================
__global__ __launch_bounds__(256, 2) void attn_fused(
    const unsigned short* __restrict__ qkv,  // [B*S,1536] bf16 q|k|v
    unsigned short* __restrict__ O) {        // [B*S,512] bf16
  __shared__ unsigned short Vt[64 * 264];  // V^T[d][k], stride 264
  __shared__ unsigned short Pl[32 * 264];  // P[q][k],  stride 264
  __shared__ float redM[4][32];
  __shared__ float redS[4][32];
  const int tid = threadIdx.x;
  const int lane = tid & 63;
  const int w = tid >> 6;
  const int r16 = lane & 15;
  const int quad = lane >> 4;
  const int h = blockIdx.x & 7;
  const int b = blockIdx.x >> 3;

  // stage V^T (verified round-2 pattern)
  {
    const int kp = w * 32 + (lane & 31);
    const int dhalf = lane >> 5;
    const unsigned short* vbase =
        qkv + (size_t)(b * 256 + 2 * kp) * 1536 + 1024 + h * 64;
    unsigned* dst = (unsigned*)Vt;
#pragma unroll
    for (int t = 0; t < 4; t++) {
      const int dc = dhalf + 2 * t;  // d-chunk 0..7
      const uint4 a = *(const uint4*)(vbase + dc * 8);
      const uint4 bb = *(const uint4*)(vbase + 1536 + dc * 8);
      const unsigned* ap = (const unsigned*)&a;
      const unsigned* bp = (const unsigned*)&bb;
#pragma unroll
      for (int i = 0; i < 4; i++) {
        const unsigned lo = ap[i], hi = bp[i];
        dst[(dc * 8 + 2 * i) * 132 + kp] = (lo & 0xffffu) | (hi << 16);
        dst[(dc * 8 + 2 * i + 1) * 132 + kp] = (lo >> 16) | (hi & 0xffff0000u);
      }
    }
  }
  __syncthreads();

  const unsigned short* krow =
      qkv + (size_t)(b * 256 + r16) * 1536 + 512 + h * 64 + quad * 8;
  const unsigned short* qrow =
      qkv + (size_t)(b * 256 + r16) * 1536 + h * 64 + quad * 8;

  for (int qt = 0; qt < 8; qt++) {
    const int q0 = qt * 32;
    f32x4 acc[4][2] = {};  // acc[mt][nt]: S^T[k=w*64+mt*16+quad*4+r][q=q0+nt*16+r16]
    bf16x8 bQ0[2], bQ1[2];
#pragma unroll
    for (int nt = 0; nt < 2; nt++) {
      const unsigned short* qp = qrow + (size_t)(q0 + nt * 16) * 1536;
      bQ0[nt] = *(const bf16x8*)(qp);
      bQ1[nt] = *(const bf16x8*)(qp + 32);
    }
#pragma unroll
    for (int mt = 0; mt < 4; mt++) {
      const unsigned short* kp = krow + (size_t)(w * 64 + mt * 16) * 1536;
      const bf16x8 aK0 = *(const bf16x8*)(kp);
      const bf16x8 aK1 = *(const bf16x8*)(kp + 32);
#pragma unroll
      for (int nt = 0; nt < 2; nt++) {
        acc[mt][nt] = __builtin_amdgcn_mfma_f32_16x16x32_bf16(aK0, bQ0[nt], acc[mt][nt], 0, 0, 0);
        acc[mt][nt] = __builtin_amdgcn_mfma_f32_16x16x32_bf16(aK1, bQ1[nt], acc[mt][nt], 0, 0, 0);
      }
    }
    // ---- merged softmax: local max + local sum, ONE cross-wave round
    float ml[2];
#pragma unroll
    for (int nt = 0; nt < 2; nt++) {
      float m = acc[0][nt][0];
#pragma unroll
      for (int mt = 0; mt < 4; mt++)
#pragma unroll
        for (int r = 0; r < 4; r++) m = fmaxf(m, acc[mt][nt][r]);
      m = fmaxf(m, __shfl_xor(m, 16));
      m = fmaxf(m, __shfl_xor(m, 32));
      ml[nt] = m;
      float s = 0.f;
#pragma unroll
      for (int mt = 0; mt < 4; mt++)
#pragma unroll
        for (int r = 0; r < 4; r++) {
          acc[mt][nt][r] = __expf((acc[mt][nt][r] - m) * 0.125f);
          s += acc[mt][nt][r];
        }
      s += __shfl_xor(s, 16);
      s += __shfl_xor(s, 32);
      if (quad == 0) {
        redM[w][nt * 16 + r16] = m;
        redS[w][nt * 16 + r16] = s;
      }
    }
    __syncthreads();
    float scale[2];
#pragma unroll
    for (int nt = 0; nt < 2; nt++) {
      const int q = nt * 16 + r16;
      const float m0_ = redM[0][q], m1_ = redM[1][q];
      const float m2_ = redM[2][q], m3_ = redM[3][q];
      const float mg = fmaxf(fmaxf(m0_, m1_), fmaxf(m2_, m3_));
      const float sg = redS[0][q] * __expf((m0_ - mg) * 0.125f) +
                       redS[1][q] * __expf((m1_ - mg) * 0.125f) +
                       redS[2][q] * __expf((m2_ - mg) * 0.125f) +
                       redS[3][q] * __expf((m3_ - mg) * 0.125f);
      scale[nt] = __expf((ml[nt] - mg) * 0.125f) / sg;
    }
#pragma unroll
    for (int nt = 0; nt < 2; nt++) {
      unsigned short* prow = Pl + (nt * 16 + r16) * 264 + w * 64 + quad * 4;
#pragma unroll
      for (int mt = 0; mt < 4; mt++) {
        uint2 u;
        u.x = pack_bf16(acc[mt][nt][0] * scale[nt], acc[mt][nt][1] * scale[nt]);
        u.y = pack_bf16(acc[mt][nt][2] * scale[nt], acc[mt][nt][3] * scale[nt]);
        *(uint2*)(prow + mt * 16) = u;
      }
    }
    __syncthreads();
    f32x4 o[2] = {};
#pragma unroll
    for (int s = 0; s < 8; s++) {
      const bf16x8 aV = *(const bf16x8*)(Vt + (w * 16 + r16) * 264 + s * 32 + quad * 8);
#pragma unroll
      for (int nt = 0; nt < 2; nt++) {
        const bf16x8 bP = *(const bf16x8*)(Pl + (nt * 16 + r16) * 264 + s * 32 + quad * 8);
        o[nt] = __builtin_amdgcn_mfma_f32_16x16x32_bf16(aV, bP, o[nt], 0, 0, 0);
      }
    }
#pragma unroll
    for (int nt = 0; nt < 2; nt++) {
      uint2 u;
      u.x = pack_bf16(o[nt][0], o[nt][1]);
      u.y = pack_bf16(o[nt][2], o[nt][3]);
      *(uint2*)(O + (size_t)(b * 256 + q0 + nt * 16 + r16) * 512 + h * 64 +
                w * 16 + quad * 4) = u;
    }
  }
}

// =====================================================================
// latent: mem[64,256] += xb[64,131072](bf16) . W[256,131072]^T
// bf16 MFMA streaming, W converted fp32->bf16 in-flight, split-K atomics.
// =====================================================================
__global__ void zero_kernel(float* __restrict__ p) {
  p[blockIdx.x * 256 + threadIdx.x] = 0.f;
}

__global__ __launch_bounds__(256) void latent_gemm(
    const unsigned short* __restrict__ xb, const float* __restrict__ W,
    float* __restrict__ mem) {
  const int tid = threadIdx.x;
  const int lane = tid & 63;
  const int w = tid >> 6;
  const int r16 = lane & 15;
  const int quad = lane >> 4;
  const int n0 = blockIdx.x * 64 + w * 16;     // wave's 16 n-rows
  const int kc0 = blockIdx.y * 1024;

  const float* wrow = W + (size_t)(n0 + r16) * 131072 + kc0 + quad * 8;
  const unsigned short* xrow = xb + (size_t)r16 * 131072 + kc0 + quad * 8;

  f32x4 c[4] = {};  // C[b = i*16+quad*4+reg][n = n0+r16]
  for (int k = 0; k < 1024; k += 32) {
    const float4 wa = *(const float4*)(wrow + k);
    const float4 wb = *(const float4*)(wrow + k + 4);
    union { unsigned u[4]; bf16x8 v; } cw;
    cw.u[0] = pack_bf16(wa.x, wa.y);
    cw.u[1] = pack_bf16(wa.z, wa.w);
    cw.u[2] = pack_bf16(wb.x, wb.y);
    cw.u[3] = pack_bf16(wb.z, wb.w);
#pragma unroll
    for (int i = 0; i < 4; i++) {
      const bf16x8 aX = *(const bf16x8*)(xrow + (size_t)i * 2097152 + k);
      c[i] = __builtin_amdgcn_mfma_f32_16x16x32_bf16(aX, cw.v, c[i], 0, 0, 0);
    }
  }
#pragma unroll
  for (int i = 0; i < 4; i++)
#pragma unroll
    for (int r = 0; r < 4; r++)
      atomicAdd(&mem[(size_t)(i * 16 + quad * 4 + r) * 256 + n0 + r16], c[i][r]);
}

// =====================================================================
__global__ __launch_bounds__(256) void head_kernel(
    const float* __restrict__ mem, const float* __restrict__ lat_b,
    const float* __restrict__ head_w, const float* __restrict__ head_b,
    float* __restrict__ out) {
  const int b = blockIdx.x;
  const int tid = threadIdx.x;
  float v = (mem[(size_t)b * 256 + tid] + lat_b[tid]) * head_w[tid];
#pragma unroll
  for (int off = 32; off > 0; off >>= 1) v += __shfl_xor(v, off);
  __shared__ float red[4];
  const int w = tid >> 6, lane = tid & 63;
  if (lane == 0) red[w] = v;
  __syncthreads();
  if (tid == 0) {
    const float z = red[0] + red[1] + red[2] + red[3] + head_b[0];
    out[b] = 1.f / (1.f + __expf(-z));
  }
}

// =====================================================================
extern "C" void kernel_launch(void* const* d_in, const int* in_sizes, int n_in,
                              void* d_out, int out_size, void* d_ws, size_t ws_size,
                              hipStream_t stream) {
  (void)in_sizes; (void)n_in; (void)out_size; (void)ws_size;
  const float* src_pad = (const float*)d_in[0];
  const float* emb_w = (const float*)d_in[1];
  const float* emb_b = (const float*)d_in[2];
  const float* qkv_w = (const float*)d_in[3];
  const float* qkv_b = (const float*)d_in[4];
  const float* out_w = (const float*)d_in[5];
  const float* out_b = (const float*)d_in[6];
  const float* ff1_w = (const float*)d_in[7];
  const float* ff1_b = (const float*)d_in[8];
  const float* ff2_w = (const float*)d_in[9];
  const float* ff2_b = (const float*)d_in[10];
  const float* ln1_g = (const float*)d_in[11];
  const float* ln1_b = (const float*)d_in[12];
  const float* ln2_g = (const float*)d_in[13];
  const float* ln2_b = (const float*)d_in[14];
  const float* lat_w = (const float*)d_in[15];
  const float* lat_b = (const float*)d_in[16];
  const float* head_w = (const float*)d_in[17];
  const float* head_b = (const float*)d_in[18];
  float* out = (float*)d_out;

  // workspace layout (~180 MB)
  char* p = (char*)d_ws;
  unsigned short* xb = (unsigned short*)p; p += (size_t)16384 * 512 * 2;  // bf16 residual stream
  unsigned short* qkv = (unsigned short*)p; p += (size_t)16384 * 1536 * 2;
  unsigned short* attno = (unsigned short*)p; p += (size_t)16384 * 512 * 2;
  unsigned short* h = (unsigned short*)p;     p += (size_t)16384 * 2048 * 2;
  unsigned short* wq = (unsigned short*)p;    p += (size_t)4718592 * 2;
  unsigned short* wo = (unsigned short*)p;    p += (size_t)1572864 * 2;
  unsigned short* wf1 = (unsigned short*)p;   p += (size_t)6291456 * 2;
  unsigned short* wf2 = (unsigned short*)p;   p += (size_t)6291456 * 2;
  float* mem = (float*)p;           p += (size_t)16384 * 4;

  cvt_all_kernel<<<18432, 256, 0, stream>>>(qkv_w, wq, out_w, wo, ff1_w, wf1,
                                            ff2_w, wf2);

  embed_kernel<<<16384, 512, 0, stream>>>(src_pad, emb_w, emb_b, xb);

  for (int l = 0; l < 6; l++) {
    // QKV: M=16384, N=1536, K=512 -> 128x128 tiles @3 blocks/CU, grid 1536
    gemm_nt<0><<<dim3(128, 12), 256, 0, stream>>>(
        xb, wq + (size_t)l * 786432, qkv_b + (size_t)l * 1536, qkv,
        16384, 1536, 512);
    attn_fused<<<512, 256, 0, stream>>>(qkv, attno);
    // out-proj + residual + LN1 fused: grid 256 (64-row blocks)
    gemm_ln<<<256, 512, 0, stream>>>(
        attno, wo + (size_t)l * 262144, out_b + (size_t)l * 512,
        ln1_g + (size_t)l * 512, ln1_b + (size_t)l * 512, xb, 512);
    // FF1 (+relu): N=2048 -> 128x128 tiles @3 blocks/CU, grid 2048
    gemm_nt<1><<<dim3(128, 16), 256, 0, stream>>>(
        xb, wf1 + (size_t)l * 1048576, ff1_b + (size_t)l * 2048, h,
        16384, 2048, 512);
    // FF2 + residual + LN2 fused: grid 256, K=2048
    gemm_ln<<<256, 512, 0, stream>>>(
        h, wf2 + (size_t)l * 1048576, ff2_b + (size_t)l * 512,
        ln2_g + (size_t)l * 512, ln2_b + (size_t)l * 512, xb, 2048);
  }

  zero_kernel<<<64, 256, 0, stream>>>(mem);
  latent_gemm<<<dim3(4, 128), 256, 0, stream>>>(xb, lat_w, mem);
  head_kernel<<<64, 256, 0, stream>>>(mem, lat_b, head_w, head_b, out);
}